// Round 1
// baseline (842.337 us; speedup 1.0000x reference)
//
#include <hip/hip_runtime.h>
#include <math.h>

// ---------------------------------------------------------------------------
// SABlock: x[B,C,H,W] -> depthwise3x3+res -> [B,N,C]: LN1 -> QKV -> MHA -> proj
//          +res -> LN2 -> FC1 -> GELU -> FC2 -> +res -> [B,C,H,W]
// Strategy: bf16 MFMA (16x16x32) for all GEMMs, fp32 residual/LN/softmax.
// GEMM skeleton = verified m97 ladder: 128x128 tile, BK=32,
// global_load_lds width 16, ds_read_b128 frags, C/D row=(lane>>4)*4+reg.
// ---------------------------------------------------------------------------

typedef __bf16 bf16;
typedef __attribute__((ext_vector_type(8))) __bf16 bf16x8;
typedef __attribute__((ext_vector_type(4))) float f32x4;

#define B_   8
#define C_   768
#define N_   1024
#define NH_  12
#define HD_  64
#define HID_ 3072
#define NTOK   (B_ * N_)     // 8192
#define NHEADS (B_ * NH_)    // 96
#define GCHUNK 12            // heads per attention chunk (S buffer = 24 MB bf16)

__device__ __forceinline__ void gload_lds16(const void* g, void* l) {
  // async 16B/lane global->LDS; LDS dest = wave-uniform base + lane*16
  __builtin_amdgcn_global_load_lds(
      (__attribute__((address_space(1))) void*)(void*)g,
      (__attribute__((address_space(3))) void*)l, 16, 0, 0);
}

// ---------------------------------------------------------------------------
// B^T GEMM: C[m][n] = sum_k A[m][k]*B[n][k], A/B bf16 row-major, acc fp32.
// WM x WN waves, each wave owns a 64x64 subtile (4x4 MFMA 16x16x32 tiles).
// EPI: 0=QKV scatter  1=scores(*0.125, batched)  2=PV->attn (batched)
//      3=resid += v+bias (proj/fc2)  4=GELU->hid (fc1)
// ---------------------------------------------------------------------------
template <int WM, int WN, int EPI>
__global__ __launch_bounds__(WM * WN * 64) void gemm_bt(
    const bf16* __restrict__ A, const bf16* __restrict__ B, int K, int lda,
    int ldb, int chunk0, bf16* __restrict__ o0, bf16* __restrict__ o1,
    bf16* __restrict__ o2, float* __restrict__ resid,
    const float* __restrict__ bias) {
  constexpr int BM = WM * 64, BN = WN * 64, T = WM * WN * 64;
  __shared__ __align__(16) bf16 As[BM * 32];
  __shared__ __align__(16) bf16 Bs[BN * 32];

  const int tid = threadIdx.x;
  const int wave = tid >> 6, lane = tid & 63;
  const int wm = wave % WM, wn = wave / WM;
  const int lr = lane & 15, kq = lane >> 4;
  const int m0 = blockIdx.y * BM, n0 = blockIdx.x * BN;

  int hh = 0;
  if constexpr (EPI == 1) {
    hh = chunk0 + blockIdx.z;
    A += (size_t)hh * N_ * HD_;
    B += (size_t)hh * N_ * HD_;
  }
  if constexpr (EPI == 2) {
    hh = chunk0 + blockIdx.z;
    A += (size_t)blockIdx.z * N_ * N_;   // P lives in the chunk-local S buffer
    B += (size_t)hh * HD_ * N_;          // V^T per head
  }

  f32x4 acc[4][4];
#pragma unroll
  for (int i = 0; i < 4; i++)
#pragma unroll
    for (int j = 0; j < 4; j++) acc[i][j] = (f32x4){0.f, 0.f, 0.f, 0.f};

  const bf16* Arow = A + (size_t)m0 * lda;
  const bf16* Brow = B + (size_t)n0 * ldb;

  for (int k0 = 0; k0 < K; k0 += 32) {
    // stage A tile: BM rows x 32 cols = BM*4 chunks of 16B
#pragma unroll
    for (int it = 0; it < (BM * 4) / T; ++it) {
      int i = it * T + tid;
      int r = i >> 2, seg = i & 3;
      gload_lds16(Arow + (size_t)r * lda + k0 + seg * 8,
                  (char*)As + (it * T + wave * 64) * 16);
    }
#pragma unroll
    for (int it = 0; it < (BN * 4) / T; ++it) {
      int i = it * T + tid;
      int r = i >> 2, seg = i & 3;
      gload_lds16(Brow + (size_t)r * ldb + k0 + seg * 8,
                  (char*)Bs + (it * T + wave * 64) * 16);
    }
    __syncthreads();  // drains vmcnt (compiler emits vmcnt(0) before barrier)

    bf16x8 af[4], bfr[4];
#pragma unroll
    for (int i = 0; i < 4; i++)
      af[i] = *(const bf16x8*)&As[(wm * 64 + i * 16 + lr) * 32 + kq * 8];
#pragma unroll
    for (int j = 0; j < 4; j++)
      bfr[j] = *(const bf16x8*)&Bs[(wn * 64 + j * 16 + lr) * 32 + kq * 8];
#pragma unroll
    for (int i = 0; i < 4; i++)
#pragma unroll
      for (int j = 0; j < 4; j++)
        acc[i][j] = __builtin_amdgcn_mfma_f32_16x16x32_bf16(af[i], bfr[j],
                                                            acc[i][j], 0, 0, 0);
    __syncthreads();
  }

  // epilogue: D element (m,n): m = m0+wm*64+i*16+kq*4+r, n = n0+wn*64+j*16+lr
#pragma unroll
  for (int i = 0; i < 4; i++) {
    const int mb = m0 + wm * 64 + i * 16 + kq * 4;
#pragma unroll
    for (int j = 0; j < 4; j++) {
      const int n = n0 + wn * 64 + j * 16 + lr;
#pragma unroll
      for (int r = 0; r < 4; r++) {
        const int m = mb + r;
        const float v = acc[i][j][r];
        if constexpr (EPI == 0) {
          int b = m >> 10, tok = m & (N_ - 1);
          int s = n / C_, rem = n - s * C_;
          int h = rem >> 6, d = rem & 63;
          size_t head = (size_t)b * NH_ + h;
          if (s == 0)
            o0[(head * N_ + tok) * HD_ + d] = (bf16)v;          // Q [head][tok][d]
          else if (s == 1)
            o1[(head * N_ + tok) * HD_ + d] = (bf16)v;          // K [head][tok][d]
          else
            o2[(head * HD_ + d) * N_ + tok] = (bf16)v;          // V^T [head][d][tok]
        } else if constexpr (EPI == 1) {
          o0[((size_t)blockIdx.z * N_ + m) * N_ + n] = (bf16)(v * 0.125f);
        } else if constexpr (EPI == 2) {
          int b = hh / NH_, h = hh - b * NH_;
          o0[((size_t)(b * N_ + m)) * C_ + h * HD_ + n] = (bf16)v;
        } else if constexpr (EPI == 3) {
          size_t o = (size_t)m * C_ + n;
          resid[o] += v + bias[n];
        } else if constexpr (EPI == 4) {
          float t = v + bias[n];
          float ge = 0.5f * t * (1.0f + erff(t * 0.70710678118654752f));
          o0[(size_t)m * HID_ + n] = (bf16)ge;
        }
      }
    }
  }
}

// ---------------------------------------------------------------------------
__global__ __launch_bounds__(256) void cast_f32_bf16(
    const float* __restrict__ in, bf16* __restrict__ out, int n) {
  int i = blockIdx.x * 256 + threadIdx.x;
  if (i < n) out[i] = (bf16)in[i];
}

// depthwise 3x3 conv, pad 1, + bias + residual; NCHW in/out (coalesced on w)
__global__ __launch_bounds__(256) void conv_dw(const float* __restrict__ x,
                                               const float* __restrict__ cw,
                                               const float* __restrict__ cb,
                                               float* __restrict__ out) {
  int idx = blockIdx.x * 256 + threadIdx.x;  // ((b*C + c)*32 + h)*32 + w
  int w = idx & 31, h = (idx >> 5) & 31;
  int bc = idx >> 10;
  int c = bc % C_;
  const float* xp = x + (size_t)bc * 1024;
  const float* wp = cw + c * 9;
  float s = cb[c];
#pragma unroll
  for (int ky = 0; ky < 3; ++ky) {
    int hh = h + ky - 1;
    if ((unsigned)hh < 32u) {
#pragma unroll
      for (int kx = 0; kx < 3; ++kx) {
        int ww = w + kx - 1;
        if ((unsigned)ww < 32u) s += xp[hh * 32 + ww] * wp[ky * 3 + kx];
      }
    }
  }
  out[idx] = xp[h * 32 + w] + s;
}

// batched 2D transpose via LDS tile: out[b][cc][r] = in[b][r][cc]
__global__ __launch_bounds__(256) void transpose_f32(
    const float* __restrict__ in, float* __restrict__ out, int R, int Cc) {
  __shared__ float tile[32][33];
  int b = blockIdx.z;
  const float* ip = in + (size_t)b * R * Cc;
  float* op = out + (size_t)b * R * Cc;
  int c0 = blockIdx.x * 32, r0 = blockIdx.y * 32;
  int tx = threadIdx.x & 31, ty = threadIdx.x >> 5;
#pragma unroll
  for (int i = 0; i < 32; i += 8)
    tile[ty + i][tx] = ip[(size_t)(r0 + ty + i) * Cc + c0 + tx];
  __syncthreads();
#pragma unroll
  for (int i = 0; i < 32; i += 8)
    op[(size_t)(c0 + ty + i) * R + r0 + tx] = tile[tx][ty + i];
}

// LayerNorm over C=768, write bf16 (GEMM A operand)
__global__ __launch_bounds__(256) void ln_bf16(const float* __restrict__ t,
                                               const float* __restrict__ g,
                                               const float* __restrict__ be,
                                               bf16* __restrict__ out) {
  int row = blockIdx.x, tid = threadIdx.x;
  const float* p = t + (size_t)row * C_;
  float v0 = p[tid], v1 = p[tid + 256], v2 = p[tid + 512];
  __shared__ float rs[256], rq[256];
  rs[tid] = v0 + v1 + v2;
  rq[tid] = v0 * v0 + v1 * v1 + v2 * v2;
  __syncthreads();
  for (int off = 128; off; off >>= 1) {
    if (tid < off) {
      rs[tid] += rs[tid + off];
      rq[tid] += rq[tid + off];
    }
    __syncthreads();
  }
  float mu = rs[0] * (1.f / C_);
  float var = rq[0] * (1.f / C_) - mu * mu;
  float rstd = rsqrtf(var + 1e-5f);
  bf16* q = out + (size_t)row * C_;
  q[tid] = (bf16)((v0 - mu) * rstd * g[tid] + be[tid]);
  q[tid + 256] = (bf16)((v1 - mu) * rstd * g[tid + 256] + be[tid + 256]);
  q[tid + 512] = (bf16)((v2 - mu) * rstd * g[tid + 512] + be[tid + 512]);
}

// softmax over rows of 1024 (bf16 in place, fp32 math)
__global__ __launch_bounds__(256) void softmax_bf16(bf16* __restrict__ S) {
  size_t row = blockIdx.x;
  int tid = threadIdx.x;
  bf16* p = S + row * N_;
  float x0 = (float)p[tid], x1 = (float)p[tid + 256];
  float x2 = (float)p[tid + 512], x3 = (float)p[tid + 768];
  __shared__ float red[256];
  red[tid] = fmaxf(fmaxf(x0, x1), fmaxf(x2, x3));
  __syncthreads();
  for (int off = 128; off; off >>= 1) {
    if (tid < off) red[tid] = fmaxf(red[tid], red[tid + off]);
    __syncthreads();
  }
  float M = red[0];
  __syncthreads();
  float e0 = __expf(x0 - M), e1 = __expf(x1 - M);
  float e2 = __expf(x2 - M), e3 = __expf(x3 - M);
  red[tid] = e0 + e1 + e2 + e3;
  __syncthreads();
  for (int off = 128; off; off >>= 1) {
    if (tid < off) red[tid] += red[tid + off];
    __syncthreads();
  }
  float inv = 1.0f / red[0];
  p[tid] = (bf16)(e0 * inv);
  p[tid + 256] = (bf16)(e1 * inv);
  p[tid + 512] = (bf16)(e2 * inv);
  p[tid + 768] = (bf16)(e3 * inv);
}

// ---------------------------------------------------------------------------
extern "C" void kernel_launch(void* const* d_in, const int* in_sizes, int n_in,
                              void* d_out, int out_size, void* d_ws,
                              size_t ws_size, hipStream_t stream) {
  (void)in_sizes; (void)n_in; (void)out_size; (void)ws_size;
  const float* x      = (const float*)d_in[0];
  const float* conv_w = (const float*)d_in[1];
  const float* conv_b = (const float*)d_in[2];
  const float* ln1_g  = (const float*)d_in[3];
  const float* ln1_b  = (const float*)d_in[4];
  const float* qkv_w  = (const float*)d_in[5];
  const float* proj_w = (const float*)d_in[6];
  const float* proj_b = (const float*)d_in[7];
  const float* ln2_g  = (const float*)d_in[8];
  const float* ln2_b  = (const float*)d_in[9];
  const float* fc1_w  = (const float*)d_in[10];
  const float* fc1_b  = (const float*)d_in[11];
  const float* fc2_w  = (const float*)d_in[12];
  const float* fc2_b  = (const float*)d_in[13];
  float* out = (float*)d_out;

  // workspace carve (all sizes multiple of 256B); total ~178 MB
  char* w = (char*)d_ws;
  auto carve = [&](size_t bytes) {
    char* p = w;
    w += (bytes + 255) & ~(size_t)255;
    return p;
  };
  bf16* hid     = (bf16*)carve((size_t)NTOK * HID_ * 2);  // 50.3MB; first 25MB aliases t_nchw
  float* t_nchw = (float*)hid;                            // conv out, dead before fc1
  float* t0     = (float*)carve((size_t)NTOK * C_ * 4);   // residual stream fp32
  bf16* lnout   = (bf16*)carve((size_t)NTOK * C_ * 2);
  bf16* wq      = (bf16*)carve((size_t)3 * C_ * C_ * 2);
  bf16* wp      = (bf16*)carve((size_t)C_ * C_ * 2);
  bf16* w1      = (bf16*)carve((size_t)HID_ * C_ * 2);
  bf16* w2      = (bf16*)carve((size_t)C_ * HID_ * 2);
  bf16* Qb      = (bf16*)carve((size_t)NHEADS * N_ * HD_ * 2);
  bf16* Kb      = (bf16*)carve((size_t)NHEADS * N_ * HD_ * 2);
  bf16* Vt      = (bf16*)carve((size_t)NHEADS * HD_ * N_ * 2);
  bf16* Sb      = (bf16*)carve((size_t)GCHUNK * N_ * N_ * 2);
  bf16* attn    = (bf16*)carve((size_t)NTOK * C_ * 2);

  // weights fp32 -> bf16
  cast_f32_bf16<<<3 * C_ * C_ / 256, 256, 0, stream>>>(qkv_w, wq, 3 * C_ * C_);
  cast_f32_bf16<<<C_ * C_ / 256, 256, 0, stream>>>(proj_w, wp, C_ * C_);
  cast_f32_bf16<<<HID_ * C_ / 256, 256, 0, stream>>>(fc1_w, w1, HID_ * C_);
  cast_f32_bf16<<<C_ * HID_ / 256, 256, 0, stream>>>(fc2_w, w2, C_ * HID_);

  // conv pos-embed + residual (NCHW), then transpose to [B,N,C]
  conv_dw<<<B_ * C_ * 1024 / 256, 256, 0, stream>>>(x, conv_w, conv_b, t_nchw);
  transpose_f32<<<dim3(N_ / 32, C_ / 32, B_), 256, 0, stream>>>(t_nchw, t0, C_, N_);

  // LN1 -> QKV (scatter to per-head Q, K, V^T)
  ln_bf16<<<NTOK, 256, 0, stream>>>(t0, ln1_g, ln1_b, lnout);
  gemm_bt<2, 2, 0><<<dim3(3 * C_ / 128, NTOK / 128), 256, 0, stream>>>(
      lnout, wq, 768, 768, 768, 0, Qb, Kb, Vt, nullptr, nullptr);

  // attention in 12-head chunks: S = QK^T*scale -> softmax -> O = P V
  for (int ch = 0; ch < NHEADS; ch += GCHUNK) {
    gemm_bt<2, 2, 1><<<dim3(8, 8, GCHUNK), 256, 0, stream>>>(
        Qb, Kb, 64, 64, 64, ch, Sb, nullptr, nullptr, nullptr, nullptr);
    softmax_bf16<<<GCHUNK * N_, 256, 0, stream>>>(Sb);
    gemm_bt<2, 1, 2><<<dim3(1, 8, GCHUNK), 128, 0, stream>>>(
        Sb, Vt, 1024, 1024, 1024, ch, attn, nullptr, nullptr, nullptr, nullptr);
  }

  // proj + residual, LN2, FC1+GELU, FC2 + residual
  gemm_bt<2, 2, 3><<<dim3(C_ / 128, NTOK / 128), 256, 0, stream>>>(
      attn, wp, 768, 768, 768, 0, nullptr, nullptr, nullptr, t0, proj_b);
  ln_bf16<<<NTOK, 256, 0, stream>>>(t0, ln2_g, ln2_b, lnout);
  gemm_bt<2, 2, 4><<<dim3(HID_ / 128, NTOK / 128), 256, 0, stream>>>(
      lnout, w1, 768, 768, 768, 0, hid, nullptr, nullptr, nullptr, fc1_b);
  gemm_bt<2, 2, 3><<<dim3(C_ / 128, NTOK / 128), 256, 0, stream>>>(
      hid, w2, 3072, 3072, 3072, 0, nullptr, nullptr, nullptr, t0, fc2_b);

  // [B,N,C] -> [B,C,H,W]
  transpose_f32<<<dim3(C_ / 32, N_ / 32, B_), 256, 0, stream>>>(t0, out, N_, C_);
}

// Round 2
// 499.018 us; speedup vs baseline: 1.6880x; 1.6880x over previous
//
#include <hip/hip_runtime.h>
#include <math.h>

// ---------------------------------------------------------------------------
// SABlock: x[B,C,H,W] -> depthwise3x3+res -> [B,N,C]: LN1 -> QKV -> flash-MHA
//          -> proj +res -> LN2 -> FC1 -> GELU -> FC2 -> +res -> [B,C,H,W]
// bf16 MFMA GEMMs (m97 skeleton + XOR-swizzled LDS), fused flash attention
// (S^T = K*Q^T form; S never hits HBM), fp32 residual/LN/softmax stats.
// ---------------------------------------------------------------------------

typedef __bf16 bf16;
typedef __attribute__((ext_vector_type(8))) __bf16 bf16x8;
typedef __attribute__((ext_vector_type(4))) __bf16 bf16x4;
typedef __attribute__((ext_vector_type(4))) float f32x4;

#define B_   8
#define C_   768
#define N_   1024
#define NH_  12
#define HD_  64
#define HID_ 3072
#define NTOK   (B_ * N_)     // 8192
#define NHEADS (B_ * NH_)    // 96
#define FA_C   0.1803368801111601f  // 0.125 * log2(e)

__device__ __forceinline__ void gload_lds16(const void* g, void* l) {
  __builtin_amdgcn_global_load_lds(
      (__attribute__((address_space(1))) void*)(void*)g,
      (__attribute__((address_space(3))) void*)l, 16, 0, 0);
}

// ---------------------------------------------------------------------------
// B^T GEMM: C[m][n] = sum_k A[m][k]*B[n][k].  XOR-swizzled BK=32 LDS tiles.
// EPI: 0=QKV scatter to per-head Q,K,V^T   3=resid += v+bias   4=GELU->hid
// ---------------------------------------------------------------------------
template <int WM, int WN, int EPI>
__global__ __launch_bounds__(WM * WN * 64) void gemm_bt(
    const bf16* __restrict__ A, const bf16* __restrict__ B, int K, int lda,
    int ldb, bf16* __restrict__ o0, bf16* __restrict__ o1,
    bf16* __restrict__ o2, float* __restrict__ resid,
    const float* __restrict__ bias) {
  constexpr int BM = WM * 64, BN = WN * 64, T = WM * WN * 64;
  __shared__ __align__(16) bf16 As[BM * 32];
  __shared__ __align__(16) bf16 Bs[BN * 32];

  const int tid = threadIdx.x;
  const int wave = tid >> 6, lane = tid & 63;
  const int wm = wave % WM, wn = wave / WM;
  const int lr = lane & 15, kq = lane >> 4;
  const int m0 = blockIdx.y * BM, n0 = blockIdx.x * BN;
  // swizzled chunk slot for fragment reads (row bits fold to lr bits)
  const int qsw = kq ^ (lr & 3) ^ ((lr >> 2) & 1);

  f32x4 acc[4][4];
#pragma unroll
  for (int i = 0; i < 4; i++)
#pragma unroll
    for (int j = 0; j < 4; j++) acc[i][j] = (f32x4){0.f, 0.f, 0.f, 0.f};

  const bf16* Arow = A + (size_t)m0 * lda;
  const bf16* Brow = B + (size_t)n0 * ldb;

  for (int k0 = 0; k0 < K; k0 += 32) {
#pragma unroll
    for (int it = 0; it < (BM * 4) / T; ++it) {
      int i = it * T + tid;
      int r = i >> 2;
      int seg = (i & 3) ^ (r & 3) ^ ((r >> 2) & 1);  // XOR swizzle, same 64B
      gload_lds16(Arow + (size_t)r * lda + k0 + seg * 8,
                  (char*)As + (it * T + wave * 64) * 16);
    }
#pragma unroll
    for (int it = 0; it < (BN * 4) / T; ++it) {
      int i = it * T + tid;
      int r = i >> 2;
      int seg = (i & 3) ^ (r & 3) ^ ((r >> 2) & 1);
      gload_lds16(Brow + (size_t)r * ldb + k0 + seg * 8,
                  (char*)Bs + (it * T + wave * 64) * 16);
    }
    __syncthreads();

    bf16x8 af[4], bfr[4];
#pragma unroll
    for (int i = 0; i < 4; i++)
      af[i] = *(const bf16x8*)&As[(wm * 64 + i * 16 + lr) * 32 + qsw * 8];
#pragma unroll
    for (int j = 0; j < 4; j++)
      bfr[j] = *(const bf16x8*)&Bs[(wn * 64 + j * 16 + lr) * 32 + qsw * 8];
#pragma unroll
    for (int i = 0; i < 4; i++)
#pragma unroll
      for (int j = 0; j < 4; j++)
        acc[i][j] = __builtin_amdgcn_mfma_f32_16x16x32_bf16(af[i], bfr[j],
                                                            acc[i][j], 0, 0, 0);
    __syncthreads();
  }

  // D element (m,n): m = m0+wm*64+i*16+kq*4+r, n = n0+wn*64+j*16+lr
#pragma unroll
  for (int i = 0; i < 4; i++) {
    const int mb = m0 + wm * 64 + i * 16 + kq * 4;
#pragma unroll
    for (int j = 0; j < 4; j++) {
      const int n = n0 + wn * 64 + j * 16 + lr;
#pragma unroll
      for (int r = 0; r < 4; r++) {
        const int m = mb + r;
        const float v = acc[i][j][r];
        if constexpr (EPI == 0) {
          int b = m >> 10, tok = m & (N_ - 1);
          int s = n / C_, rem = n - s * C_;
          int h = rem >> 6, d = rem & 63;
          size_t head = (size_t)b * NH_ + h;
          if (s == 0)
            o0[(head * N_ + tok) * HD_ + d] = (bf16)v;     // Q [head][tok][d]
          else if (s == 1)
            o1[(head * N_ + tok) * HD_ + d] = (bf16)v;     // K [head][tok][d]
          else
            o2[(head * HD_ + d) * N_ + tok] = (bf16)v;     // V^T [head][d][tok]
        } else if constexpr (EPI == 3) {
          resid[(size_t)m * C_ + n] += v + bias[n];
        } else if constexpr (EPI == 4) {
          float t = v + bias[n];
          float ge = 0.5f * t * (1.0f + erff(t * 0.70710678118654752f));
          o0[(size_t)m * HID_ + n] = (bf16)ge;
        }
      }
    }
  }
}

// ---------------------------------------------------------------------------
// Flash attention: grid (8 q-tiles, 96 heads), 256 thr. Wave owns 32 q-rows.
// S^T = K*Q^T (Q in regs), online softmax (stats via 2 shuffles), P via LDS
// (XOR-swizzled, packed 8B writes), O^T += V^T * P.  LDS = 64 KB exactly.
// ---------------------------------------------------------------------------
__global__ __launch_bounds__(256, 2) void flash_attn(
    const bf16* __restrict__ Qb, const bf16* __restrict__ Kb,
    const bf16* __restrict__ Vt, bf16* __restrict__ attn) {
  __shared__ __align__(16) bf16 ksm[128 * 64];      // 16 KB: K tile, swizzled
  __shared__ __align__(16) bf16 vsm[64 * 128];      // 16 KB: V^T tile, swizzled
  __shared__ __align__(16) bf16 psm[4][32][128];    // 32 KB: per-wave P

  const int tid = threadIdx.x, wave = tid >> 6, lane = tid & 63;
  const int lr = lane & 15, kq = lane >> 4;
  const int head = blockIdx.y;
  const int b = head / NH_, hh = head - b * NH_;
  const int q0 = blockIdx.x * 128;
  const bf16* Qh = Qb + (size_t)head * (N_ * HD_);
  const bf16* Kh = Kb + (size_t)head * (N_ * HD_);
  const bf16* Vh = Vt + (size_t)head * (HD_ * N_);
  bf16* pw = &psm[wave][0][0];

  // Q fragments in registers: row = q0 + wave*32 + j*16 + lr, k = kh*32+kq*8
  bf16x8 qf[2][2];
#pragma unroll
  for (int j = 0; j < 2; ++j)
#pragma unroll
    for (int kh = 0; kh < 2; ++kh)
      qf[j][kh] = *(const bf16x8*)(Qh + (size_t)(q0 + wave * 32 + j * 16 + lr) * HD_ +
                                   kh * 32 + kq * 8);

  f32x4 o[4][2];
#pragma unroll
  for (int i = 0; i < 4; i++)
#pragma unroll
    for (int j = 0; j < 2; j++) o[i][j] = (f32x4){0.f, 0.f, 0.f, 0.f};
  float mprev[2] = {-1e30f, -1e30f}, lacc[2] = {0.f, 0.f};

  for (int t = 0; t < 8; ++t) {
    // stage K tile [128 tok][64 d]: 8 chunks/row, chunk slot = c ^ (row&7)
#pragma unroll
    for (int it = 0; it < 4; ++it) {
      int s = it * 256 + tid;
      int r = s >> 3, seg = (s & 7) ^ (r & 7);
      gload_lds16(Kh + (size_t)(t * 128 + r) * HD_ + seg * 8,
                  (char*)ksm + (it * 256 + wave * 64) * 16);
    }
    // stage V^T tile [64 d][128 tok]: 16 chunks/row, slot = c ^ (row&15)
#pragma unroll
    for (int it = 0; it < 4; ++it) {
      int s = it * 256 + tid;
      int r = s >> 4, seg = (s & 15) ^ (r & 15);
      gload_lds16(Vh + (size_t)r * N_ + t * 128 + seg * 8,
                  (char*)vsm + (it * 256 + wave * 64) * 16);
    }
    __syncthreads();

    // S^T tile: C[ktok=i*16+kq*4+r][qrow=j*16+lr]
    f32x4 sacc[8][2];
#pragma unroll
    for (int i = 0; i < 8; ++i) {
#pragma unroll
      for (int j = 0; j < 2; ++j) sacc[i][j] = (f32x4){0.f, 0.f, 0.f, 0.f};
      int row = i * 16 + lr;
      bf16x8 kf0 = *(const bf16x8*)((char*)ksm + row * 128 + ((kq ^ (row & 7)) * 16));
      bf16x8 kf1 = *(const bf16x8*)((char*)ksm + row * 128 + (((kq + 4) ^ (row & 7)) * 16));
#pragma unroll
      for (int j = 0; j < 2; ++j) {
        sacc[i][j] = __builtin_amdgcn_mfma_f32_16x16x32_bf16(kf0, qf[j][0], sacc[i][j], 0, 0, 0);
        sacc[i][j] = __builtin_amdgcn_mfma_f32_16x16x32_bf16(kf1, qf[j][1], sacc[i][j], 0, 0, 0);
      }
    }

    // online softmax per j (qrow = j*16+lr); P written to LDS as bf16
#pragma unroll
    for (int j = 0; j < 2; ++j) {
      float mx = -1e30f;
#pragma unroll
      for (int i = 0; i < 8; ++i)
#pragma unroll
        for (int r = 0; r < 4; ++r) mx = fmaxf(mx, sacc[i][j][r]);
      mx = fmaxf(mx, __shfl_xor(mx, 16));
      mx = fmaxf(mx, __shfl_xor(mx, 32));
      float mnew = fmaxf(mprev[j], mx);
      float alpha = exp2f((mprev[j] - mnew) * FA_C);
      mprev[j] = mnew;
      float rs = 0.f;
      const int prow = j * 16 + lr;
#pragma unroll
      for (int i = 0; i < 8; ++i) {
        float p0 = exp2f((sacc[i][j][0] - mnew) * FA_C);
        float p1 = exp2f((sacc[i][j][1] - mnew) * FA_C);
        float p2 = exp2f((sacc[i][j][2] - mnew) * FA_C);
        float p3 = exp2f((sacc[i][j][3] - mnew) * FA_C);
        rs += (p0 + p1) + (p2 + p3);
        bf16x4 pk = {(bf16)p0, (bf16)p1, (bf16)p2, (bf16)p3};
        // col base = i*16+kq*4 -> chunk c = i*2+(kq>>1), +8B if kq odd
        int c = i * 2 + (kq >> 1);
        *(bf16x4*)((char*)pw + prow * 256 + ((c ^ (prow & 15)) * 16) + (kq & 1) * 8) = pk;
      }
      rs += __shfl_xor(rs, 16);
      rs += __shfl_xor(rs, 32);
      lacc[j] = lacc[j] * alpha + rs;
#pragma unroll
      for (int i = 0; i < 4; ++i) {
        o[i][j][0] *= alpha; o[i][j][1] *= alpha;
        o[i][j][2] *= alpha; o[i][j][3] *= alpha;
      }
    }

    // O^T += V^T * P : C[d=i*16+kq*4+r][qrow=j*16+lr]  (same-wave LDS RAW: DS in-order)
#pragma unroll
    for (int k0c = 0; k0c < 4; ++k0c) {
      bf16x8 pf[2];
#pragma unroll
      for (int j = 0; j < 2; ++j) {
        int prow = j * 16 + lr, c = k0c * 4 + kq;
        pf[j] = *(const bf16x8*)((char*)pw + prow * 256 + ((c ^ (prow & 15)) * 16));
      }
#pragma unroll
      for (int i = 0; i < 4; ++i) {
        int d = i * 16 + lr, c = k0c * 4 + kq;
        bf16x8 vf = *(const bf16x8*)((char*)vsm + d * 256 + ((c ^ (d & 15)) * 16));
#pragma unroll
        for (int j = 0; j < 2; ++j)
          o[i][j] = __builtin_amdgcn_mfma_f32_16x16x32_bf16(vf, pf[j], o[i][j], 0, 0, 0);
      }
    }
    __syncthreads();
  }

  // epilogue: attn[b][tok][hh*64 + d], packed 4 bf16 (consecutive d)
#pragma unroll
  for (int j = 0; j < 2; ++j) {
    float inv = 1.0f / lacc[j];
    int tok = q0 + wave * 32 + j * 16 + lr;
    bf16* op = attn + ((size_t)(b * N_ + tok)) * C_ + hh * HD_;
#pragma unroll
    for (int i = 0; i < 4; ++i) {
      bf16x4 pk = {(bf16)(o[i][j][0] * inv), (bf16)(o[i][j][1] * inv),
                   (bf16)(o[i][j][2] * inv), (bf16)(o[i][j][3] * inv)};
      *(bf16x4*)(op + i * 16 + kq * 4) = pk;
    }
  }
}

// ---------------------------------------------------------------------------
// merged weight cast fp32->bf16 (4 sources, contiguous dst), float4 vectorized
__global__ __launch_bounds__(256) void cast_all(
    const float* __restrict__ a, int na, const float* __restrict__ b, int nb,
    const float* __restrict__ c, int nc, const float* __restrict__ d,
    bf16* __restrict__ dst) {
  int i = (blockIdx.x * 256 + threadIdx.x) * 4;
  const float* src;
  int off;
  if (i < na) { src = a; off = i; }
  else if (i < na + nb) { src = b; off = i - na; }
  else if (i < na + nb + nc) { src = c; off = i - na - nb; }
  else { src = d; off = i - na - nb - nc; }
  float4 v = *(const float4*)(src + off);
  bf16x4 o = {(bf16)v.x, (bf16)v.y, (bf16)v.z, (bf16)v.w};
  *(bf16x4*)(dst + i) = o;
}

// depthwise 3x3 conv + bias + residual, fused transpose NCHW -> [B,N,C]
__global__ __launch_bounds__(256) void conv_pe_t(const float* __restrict__ x,
                                                 const float* __restrict__ cw,
                                                 const float* __restrict__ cb,
                                                 float* __restrict__ t0) {
  __shared__ float tile[32][33];
  const int h = blockIdx.x, ct = blockIdx.y, b = blockIdx.z;
  const int tid = threadIdx.x;
  const int w = tid & 31, cs = tid >> 5;
#pragma unroll
  for (int cc = cs; cc < 32; cc += 8) {
    int c = ct * 32 + cc;
    const float* xp = x + ((size_t)(b * C_ + c)) * 1024;
    const float* wp = cw + c * 9;
    float s = cb[c] + xp[h * 32 + w];
#pragma unroll
    for (int ky = 0; ky < 3; ++ky) {
      int hy = h + ky - 1;
      if ((unsigned)hy < 32u) {
#pragma unroll
        for (int kx = 0; kx < 3; ++kx) {
          int wx = w + kx - 1;
          if ((unsigned)wx < 32u) s += xp[hy * 32 + wx] * wp[ky * 3 + kx];
        }
      }
    }
    tile[cc][w] = s;
  }
  __syncthreads();
  const int cc = tid & 31;
#pragma unroll
  for (int wc = tid >> 5; wc < 32; wc += 8)
    t0[((size_t)(b * N_) + h * 32 + wc) * C_ + ct * 32 + cc] = tile[cc][wc];
}

// LayerNorm over C=768, fp32 in, bf16 out
__global__ __launch_bounds__(256) void ln_bf16(const float* __restrict__ t,
                                               const float* __restrict__ g,
                                               const float* __restrict__ be,
                                               bf16* __restrict__ out) {
  int row = blockIdx.x, tid = threadIdx.x;
  const float* p = t + (size_t)row * C_;
  float v0 = p[tid], v1 = p[tid + 256], v2 = p[tid + 512];
  __shared__ float rs[256], rq[256];
  rs[tid] = v0 + v1 + v2;
  rq[tid] = v0 * v0 + v1 * v1 + v2 * v2;
  __syncthreads();
  for (int off = 128; off; off >>= 1) {
    if (tid < off) {
      rs[tid] += rs[tid + off];
      rq[tid] += rq[tid + off];
    }
    __syncthreads();
  }
  float mu = rs[0] * (1.f / C_);
  float var = rq[0] * (1.f / C_) - mu * mu;
  float rstd = rsqrtf(var + 1e-5f);
  bf16* q = out + (size_t)row * C_;
  q[tid] = (bf16)((v0 - mu) * rstd * g[tid] + be[tid]);
  q[tid + 256] = (bf16)((v1 - mu) * rstd * g[tid + 256] + be[tid + 256]);
  q[tid + 512] = (bf16)((v2 - mu) * rstd * g[tid + 512] + be[tid + 512]);
}

// batched 2D transpose via LDS: out[b][cc][r] = in[b][r][cc]
__global__ __launch_bounds__(256) void transpose_f32(
    const float* __restrict__ in, float* __restrict__ out, int R, int Cc) {
  __shared__ float tile[32][33];
  int b = blockIdx.z;
  const float* ip = in + (size_t)b * R * Cc;
  float* op = out + (size_t)b * R * Cc;
  int c0 = blockIdx.x * 32, r0 = blockIdx.y * 32;
  int tx = threadIdx.x & 31, ty = threadIdx.x >> 5;
#pragma unroll
  for (int i = 0; i < 32; i += 8)
    tile[ty + i][tx] = ip[(size_t)(r0 + ty + i) * Cc + c0 + tx];
  __syncthreads();
#pragma unroll
  for (int i = 0; i < 32; i += 8)
    op[(size_t)(c0 + ty + i) * R + r0 + tx] = tile[tx][ty + i];
}

// ---------------------------------------------------------------------------
extern "C" void kernel_launch(void* const* d_in, const int* in_sizes, int n_in,
                              void* d_out, int out_size, void* d_ws,
                              size_t ws_size, hipStream_t stream) {
  (void)in_sizes; (void)n_in; (void)out_size; (void)ws_size;
  const float* x      = (const float*)d_in[0];
  const float* conv_w = (const float*)d_in[1];
  const float* conv_b = (const float*)d_in[2];
  const float* ln1_g  = (const float*)d_in[3];
  const float* ln1_b  = (const float*)d_in[4];
  const float* qkv_w  = (const float*)d_in[5];
  const float* proj_w = (const float*)d_in[6];
  const float* proj_b = (const float*)d_in[7];
  const float* ln2_g  = (const float*)d_in[8];
  const float* ln2_b  = (const float*)d_in[9];
  const float* fc1_w  = (const float*)d_in[10];
  const float* fc1_b  = (const float*)d_in[11];
  const float* fc2_w  = (const float*)d_in[12];
  const float* fc2_b  = (const float*)d_in[13];
  float* out = (float*)d_out;

  char* w = (char*)d_ws;
  auto carve = [&](size_t bytes) {
    char* p = w;
    w += (bytes + 255) & ~(size_t)255;
    return p;
  };
  bf16* hid   = (bf16*)carve((size_t)NTOK * HID_ * 2);   // 50.3 MB
  float* t0   = (float*)carve((size_t)NTOK * C_ * 4);    // residual fp32
  bf16* lnout = (bf16*)carve((size_t)NTOK * C_ * 2);
  bf16* wq    = (bf16*)carve((size_t)3 * C_ * C_ * 2);   // wq/wp/w1/w2 contiguous
  bf16* wp    = (bf16*)carve((size_t)C_ * C_ * 2);
  bf16* w1    = (bf16*)carve((size_t)HID_ * C_ * 2);
  bf16* w2    = (bf16*)carve((size_t)C_ * HID_ * 2);
  bf16* Qb    = (bf16*)carve((size_t)NHEADS * N_ * HD_ * 2);
  bf16* Kb    = (bf16*)carve((size_t)NHEADS * N_ * HD_ * 2);
  bf16* Vt    = (bf16*)carve((size_t)NHEADS * HD_ * N_ * 2);
  bf16* attn  = (bf16*)carve((size_t)NTOK * C_ * 2);
  (void)wp; (void)w1; (void)w2;

  const int na = 3 * C_ * C_, nb = C_ * C_, nc = HID_ * C_, nd = C_ * HID_;
  cast_all<<<(na + nb + nc + nd) / 1024, 256, 0, stream>>>(
      qkv_w, na, proj_w, nb, fc1_w, nc, fc2_w, wq);

  conv_pe_t<<<dim3(32, C_ / 32, B_), 256, 0, stream>>>(x, conv_w, conv_b, t0);

  ln_bf16<<<NTOK, 256, 0, stream>>>(t0, ln1_g, ln1_b, lnout);
  gemm_bt<2, 2, 0><<<dim3(3 * C_ / 128, NTOK / 128), 256, 0, stream>>>(
      lnout, wq, 768, 768, 768, Qb, Kb, Vt, nullptr, nullptr);

  flash_attn<<<dim3(N_ / 128, NHEADS), 256, 0, stream>>>(Qb, Kb, Vt, attn);

  gemm_bt<2, 2, 3><<<dim3(C_ / 128, NTOK / 128), 256, 0, stream>>>(
      attn, wp, 768, 768, 768, nullptr, nullptr, nullptr, t0, proj_b);
  ln_bf16<<<NTOK, 256, 0, stream>>>(t0, ln2_g, ln2_b, lnout);
  gemm_bt<2, 2, 4><<<dim3(HID_ / 128, NTOK / 128), 256, 0, stream>>>(
      lnout, w1, 768, 768, 768, hid, nullptr, nullptr, nullptr, fc1_b);
  gemm_bt<2, 2, 3><<<dim3(C_ / 128, NTOK / 128), 256, 0, stream>>>(
      hid, w2, 3072, 3072, 3072, nullptr, nullptr, nullptr, t0, fc2_b);

  transpose_f32<<<dim3(C_ / 32, N_ / 32, B_), 256, 0, stream>>>(t0, out, N_, C_);
}

// Round 3
// 485.852 us; speedup vs baseline: 1.7337x; 1.0271x over previous
//
#include <hip/hip_runtime.h>
#include <math.h>

// ---------------------------------------------------------------------------
// SABlock: x[B,C,H,W] -> depthwise3x3+res -> [B,N,C]: LN1 -> QKV -> flash-MHA
//          -> proj +res -> LN2 -> FC1 -> GELU -> FC2 -> +res -> [B,C,H,W]
// bf16 MFMA GEMMs (m97 skeleton), flash attention v2: K-tile 64, double-
// buffered global_load_lds pipeline (stage t+1 overlaps compute t), 48 KB LDS
// -> 3 blocks/CU so the whole grid is co-resident.
// ---------------------------------------------------------------------------

typedef __bf16 bf16;
typedef __attribute__((ext_vector_type(8))) __bf16 bf16x8;
typedef __attribute__((ext_vector_type(4))) __bf16 bf16x4;
typedef __attribute__((ext_vector_type(4))) float f32x4;

#define B_   8
#define C_   768
#define N_   1024
#define NH_  12
#define HD_  64
#define HID_ 3072
#define NTOK   (B_ * N_)     // 8192
#define NHEADS (B_ * NH_)    // 96
#define FA_C   0.1803368801111601f  // 0.125 * log2(e)

__device__ __forceinline__ void gload_lds16(const void* g, void* l) {
  __builtin_amdgcn_global_load_lds(
      (__attribute__((address_space(1))) void*)(void*)g,
      (__attribute__((address_space(3))) void*)l, 16, 0, 0);
}

// ---------------------------------------------------------------------------
// B^T GEMM: C[m][n] = sum_k A[m][k]*B[n][k].  BK=32 LDS tiles.
// EPI: 0=QKV scatter to per-head Q,K,V^T   3=resid += v+bias   4=GELU->hid
// ---------------------------------------------------------------------------
template <int WM, int WN, int EPI>
__global__ __launch_bounds__(WM * WN * 64) void gemm_bt(
    const bf16* __restrict__ A, const bf16* __restrict__ B, int K, int lda,
    int ldb, bf16* __restrict__ o0, bf16* __restrict__ o1,
    bf16* __restrict__ o2, float* __restrict__ resid,
    const float* __restrict__ bias) {
  constexpr int BM = WM * 64, BN = WN * 64, T = WM * WN * 64;
  __shared__ __align__(16) bf16 As[BM * 32];
  __shared__ __align__(16) bf16 Bs[BN * 32];

  const int tid = threadIdx.x;
  const int wave = tid >> 6, lane = tid & 63;
  const int wm = wave % WM, wn = wave / WM;
  const int lr = lane & 15, kq = lane >> 4;
  const int m0 = blockIdx.y * BM, n0 = blockIdx.x * BN;

  f32x4 acc[4][4];
#pragma unroll
  for (int i = 0; i < 4; i++)
#pragma unroll
    for (int j = 0; j < 4; j++) acc[i][j] = (f32x4){0.f, 0.f, 0.f, 0.f};

  const bf16* Arow = A + (size_t)m0 * lda;
  const bf16* Brow = B + (size_t)n0 * ldb;

  for (int k0 = 0; k0 < K; k0 += 32) {
#pragma unroll
    for (int it = 0; it < (BM * 4) / T; ++it) {
      int i = it * T + tid;
      int r = i >> 2, seg = i & 3;
      gload_lds16(Arow + (size_t)r * lda + k0 + seg * 8,
                  (char*)As + (it * T + wave * 64) * 16);
    }
#pragma unroll
    for (int it = 0; it < (BN * 4) / T; ++it) {
      int i = it * T + tid;
      int r = i >> 2, seg = i & 3;
      gload_lds16(Brow + (size_t)r * ldb + k0 + seg * 8,
                  (char*)Bs + (it * T + wave * 64) * 16);
    }
    __syncthreads();

    bf16x8 af[4], bfr[4];
#pragma unroll
    for (int i = 0; i < 4; i++)
      af[i] = *(const bf16x8*)&As[(wm * 64 + i * 16 + lr) * 32 + kq * 8];
#pragma unroll
    for (int j = 0; j < 4; j++)
      bfr[j] = *(const bf16x8*)&Bs[(wn * 64 + j * 16 + lr) * 32 + kq * 8];
#pragma unroll
    for (int i = 0; i < 4; i++)
#pragma unroll
      for (int j = 0; j < 4; j++)
        acc[i][j] = __builtin_amdgcn_mfma_f32_16x16x32_bf16(af[i], bfr[j],
                                                            acc[i][j], 0, 0, 0);
    __syncthreads();
  }

  // D element (m,n): m = m0+wm*64+i*16+kq*4+r, n = n0+wn*64+j*16+lr
#pragma unroll
  for (int i = 0; i < 4; i++) {
    const int mb = m0 + wm * 64 + i * 16 + kq * 4;
#pragma unroll
    for (int j = 0; j < 4; j++) {
      const int n = n0 + wn * 64 + j * 16 + lr;
#pragma unroll
      for (int r = 0; r < 4; r++) {
        const int m = mb + r;
        const float v = acc[i][j][r];
        if constexpr (EPI == 0) {
          int b = m >> 10, tok = m & (N_ - 1);
          int s = n / C_, rem = n - s * C_;
          int h = rem >> 6, d = rem & 63;
          size_t head = (size_t)b * NH_ + h;
          if (s == 0)
            o0[(head * N_ + tok) * HD_ + d] = (bf16)v;     // Q [head][tok][d]
          else if (s == 1)
            o1[(head * N_ + tok) * HD_ + d] = (bf16)v;     // K [head][tok][d]
          else
            o2[(head * HD_ + d) * N_ + tok] = (bf16)v;     // V^T [head][d][tok]
        } else if constexpr (EPI == 3) {
          resid[(size_t)m * C_ + n] += v + bias[n];
        } else if constexpr (EPI == 4) {
          float t = v + bias[n];
          float ge = 0.5f * t * (1.0f + erff(t * 0.70710678118654752f));
          o0[(size_t)m * HID_ + n] = (bf16)ge;
        }
      }
    }
  }
}

// ---------------------------------------------------------------------------
// Flash attention v2: grid (8 q-tiles, 96 heads) = 768 blocks, 256 thr.
// Wave owns 32 q-rows. 16 K-tiles of 64, double-buffered staging:
//   sync; stage(t+1 -> buf^1); compute(t, buf)   -- vmcnt drain at NEXT sync.
// LDS 48 KB -> 3 blocks/CU: whole grid co-resident.
// ---------------------------------------------------------------------------
__global__ __launch_bounds__(256, 3) void flash_attn(
    const bf16* __restrict__ Qb, const bf16* __restrict__ Kb,
    const bf16* __restrict__ Vt, bf16* __restrict__ attn) {
  __shared__ __align__(16) bf16 ksm[2][64 * 64];   // 2 x 8 KB, swizzled
  __shared__ __align__(16) bf16 vsm[2][64 * 64];   // 2 x 8 KB, swizzled
  __shared__ __align__(16) bf16 psm[4][32 * 64];   // 4 KB per wave (both j)

  const int tid = threadIdx.x, wave = tid >> 6, lane = tid & 63;
  const int lr = lane & 15, kq = lane >> 4;
  const int head = blockIdx.y;
  const int b = head / NH_, hh = head - b * NH_;
  const int q0 = blockIdx.x * 128;
  const bf16* Qh = Qb + (size_t)head * (N_ * HD_);
  const bf16* Kh = Kb + (size_t)head * (N_ * HD_);
  const bf16* Vh = Vt + (size_t)head * (HD_ * N_);
  char* pw = (char*)&psm[wave][0];

  // Q fragments in registers: qrow = q0+wave*32+j*16+lr, k = kh*32+kq*8
  bf16x8 qf[2][2];
#pragma unroll
  for (int j = 0; j < 2; ++j)
#pragma unroll
    for (int kh = 0; kh < 2; ++kh)
      qf[j][kh] = *(const bf16x8*)(Qh +
                                   (size_t)(q0 + wave * 32 + j * 16 + lr) * HD_ +
                                   kh * 32 + kq * 8);

  f32x4 o[4][2];
#pragma unroll
  for (int i = 0; i < 4; i++)
#pragma unroll
    for (int j = 0; j < 2; j++) o[i][j] = (f32x4){0.f, 0.f, 0.f, 0.f};
  float mprev[2] = {-1e30f, -1e30f}, lacc[2] = {0.f, 0.f};

  // stage K/V tile t into buffer bi: 64 rows x 64 elems, 8 x 16B chunks/row,
  // chunk slot swizzled by row&7
  auto stage = [&](int t, int bi) {
#pragma unroll
    for (int it = 0; it < 2; ++it) {
      int s = it * 256 + tid;
      int r = s >> 3, seg = (s & 7) ^ (r & 7);
      gload_lds16(Kh + (size_t)(t * 64 + r) * HD_ + seg * 8,
                  (char*)ksm[bi] + (it * 256 + wave * 64) * 16);
    }
#pragma unroll
    for (int it = 0; it < 2; ++it) {
      int s = it * 256 + tid;
      int r = s >> 3, seg = (s & 7) ^ (r & 7);
      gload_lds16(Vh + (size_t)r * N_ + t * 64 + seg * 8,
                  (char*)vsm[bi] + (it * 256 + wave * 64) * 16);
    }
  };

  stage(0, 0);

  for (int t = 0; t < 16; ++t) {
    const int bi = t & 1;
    __syncthreads();               // drains stage(t); all waves done with t-1
    if (t < 15) stage(t + 1, bi ^ 1);

    // S^T tile [64 ktok][32 qrow]: sacc[i][j], ktok = i*16+kq*4+r, qrow=j*16+lr
    f32x4 sacc[4][2];
#pragma unroll
    for (int i = 0; i < 4; ++i) {
#pragma unroll
      for (int j = 0; j < 2; ++j) sacc[i][j] = (f32x4){0.f, 0.f, 0.f, 0.f};
      int row = i * 16 + lr;
      bf16x8 kf0 = *(const bf16x8*)((char*)ksm[bi] + row * 128 +
                                    ((kq ^ (row & 7)) * 16));
      bf16x8 kf1 = *(const bf16x8*)((char*)ksm[bi] + row * 128 +
                                    (((4 + kq) ^ (row & 7)) * 16));
#pragma unroll
      for (int j = 0; j < 2; ++j) {
        sacc[i][j] = __builtin_amdgcn_mfma_f32_16x16x32_bf16(kf0, qf[j][0],
                                                             sacc[i][j], 0, 0, 0);
        sacc[i][j] = __builtin_amdgcn_mfma_f32_16x16x32_bf16(kf1, qf[j][1],
                                                             sacc[i][j], 0, 0, 0);
      }
    }

    // online softmax (both j interleaved); P -> LDS bf16 (packed 8B writes)
#pragma unroll
    for (int j = 0; j < 2; ++j) {
      float mx = -1e30f;
#pragma unroll
      for (int i = 0; i < 4; ++i)
#pragma unroll
        for (int r = 0; r < 4; ++r) mx = fmaxf(mx, sacc[i][j][r]);
      mx = fmaxf(mx, __shfl_xor(mx, 16));
      mx = fmaxf(mx, __shfl_xor(mx, 32));
      float mnew = fmaxf(mprev[j], mx);
      float alpha = __builtin_amdgcn_exp2f((mprev[j] - mnew) * FA_C);
      mprev[j] = mnew;
      float rs = 0.f;
      const int prow = j * 16 + lr;
#pragma unroll
      for (int i = 0; i < 4; ++i) {
        float p0 = __builtin_amdgcn_exp2f((sacc[i][j][0] - mnew) * FA_C);
        float p1 = __builtin_amdgcn_exp2f((sacc[i][j][1] - mnew) * FA_C);
        float p2 = __builtin_amdgcn_exp2f((sacc[i][j][2] - mnew) * FA_C);
        float p3 = __builtin_amdgcn_exp2f((sacc[i][j][3] - mnew) * FA_C);
        rs += (p0 + p1) + (p2 + p3);
        bf16x4 pk = {(bf16)p0, (bf16)p1, (bf16)p2, (bf16)p3};
        int c = i * 2 + (kq >> 1);   // ktok chunk (8 elems) within 64
        *(bf16x4*)(pw + prow * 128 + ((c ^ (prow & 7)) * 16) + (kq & 1) * 8) = pk;
      }
      rs += __shfl_xor(rs, 16);
      rs += __shfl_xor(rs, 32);
      lacc[j] = lacc[j] * alpha + rs;
#pragma unroll
      for (int i = 0; i < 4; ++i) {
        o[i][j][0] *= alpha; o[i][j][1] *= alpha;
        o[i][j][2] *= alpha; o[i][j][3] *= alpha;
      }
    }

    // O^T += V^T * P : d = i*16+kq*4+r, qrow = j*16+lr  (same-wave LDS RAW)
#pragma unroll
    for (int k0c = 0; k0c < 2; ++k0c) {
      bf16x8 pf[2];
#pragma unroll
      for (int j = 0; j < 2; ++j) {
        int prow = j * 16 + lr, c = k0c * 4 + kq;
        pf[j] = *(const bf16x8*)(pw + prow * 128 + ((c ^ (prow & 7)) * 16));
      }
#pragma unroll
      for (int i = 0; i < 4; ++i) {
        int d = i * 16 + lr, c = k0c * 4 + kq;
        bf16x8 vf = *(const bf16x8*)((char*)vsm[bi] + d * 128 +
                                     ((c ^ (d & 7)) * 16));
#pragma unroll
        for (int j = 0; j < 2; ++j)
          o[i][j] = __builtin_amdgcn_mfma_f32_16x16x32_bf16(vf, pf[j], o[i][j],
                                                            0, 0, 0);
      }
    }
  }

  // epilogue: attn[b][tok][hh*64 + d]
#pragma unroll
  for (int j = 0; j < 2; ++j) {
    float inv = 1.0f / lacc[j];
    int tok = q0 + wave * 32 + j * 16 + lr;
    bf16* op = attn + ((size_t)(b * N_ + tok)) * C_ + hh * HD_;
#pragma unroll
    for (int i = 0; i < 4; ++i) {
      bf16x4 pk = {(bf16)(o[i][j][0] * inv), (bf16)(o[i][j][1] * inv),
                   (bf16)(o[i][j][2] * inv), (bf16)(o[i][j][3] * inv)};
      *(bf16x4*)(op + i * 16 + kq * 4) = pk;
    }
  }
}

// ---------------------------------------------------------------------------
// merged weight cast fp32->bf16 (4 sources, contiguous dst), float4 vectorized
__global__ __launch_bounds__(256) void cast_all(
    const float* __restrict__ a, int na, const float* __restrict__ b, int nb,
    const float* __restrict__ c, int nc, const float* __restrict__ d,
    bf16* __restrict__ dst) {
  int i = (blockIdx.x * 256 + threadIdx.x) * 4;
  const float* src;
  int off;
  if (i < na) { src = a; off = i; }
  else if (i < na + nb) { src = b; off = i - na; }
  else if (i < na + nb + nc) { src = c; off = i - na - nb; }
  else { src = d; off = i - na - nb - nc; }
  float4 v = *(const float4*)(src + off);
  bf16x4 o = {(bf16)v.x, (bf16)v.y, (bf16)v.z, (bf16)v.w};
  *(bf16x4*)(dst + i) = o;
}

// depthwise 3x3 conv + bias + residual, fused transpose NCHW -> [B,N,C]
__global__ __launch_bounds__(256) void conv_pe_t(const float* __restrict__ x,
                                                 const float* __restrict__ cw,
                                                 const float* __restrict__ cb,
                                                 float* __restrict__ t0) {
  __shared__ float tile[32][33];
  const int h = blockIdx.x, ct = blockIdx.y, b = blockIdx.z;
  const int tid = threadIdx.x;
  const int w = tid & 31, cs = tid >> 5;
#pragma unroll
  for (int cc = cs; cc < 32; cc += 8) {
    int c = ct * 32 + cc;
    const float* xp = x + ((size_t)(b * C_ + c)) * 1024;
    const float* wp = cw + c * 9;
    float s = cb[c] + xp[h * 32 + w];
#pragma unroll
    for (int ky = 0; ky < 3; ++ky) {
      int hy = h + ky - 1;
      if ((unsigned)hy < 32u) {
#pragma unroll
        for (int kx = 0; kx < 3; ++kx) {
          int wx = w + kx - 1;
          if ((unsigned)wx < 32u) s += xp[hy * 32 + wx] * wp[ky * 3 + kx];
        }
      }
    }
    tile[cc][w] = s;
  }
  __syncthreads();
  const int cc = tid & 31;
#pragma unroll
  for (int wc = tid >> 5; wc < 32; wc += 8)
    t0[((size_t)(b * N_) + h * 32 + wc) * C_ + ct * 32 + cc] = tile[cc][wc];
}

// LayerNorm over C=768, fp32 in, bf16 out
__global__ __launch_bounds__(256) void ln_bf16(const float* __restrict__ t,
                                               const float* __restrict__ g,
                                               const float* __restrict__ be,
                                               bf16* __restrict__ out) {
  int row = blockIdx.x, tid = threadIdx.x;
  const float* p = t + (size_t)row * C_;
  float v0 = p[tid], v1 = p[tid + 256], v2 = p[tid + 512];
  __shared__ float rs[256], rq[256];
  rs[tid] = v0 + v1 + v2;
  rq[tid] = v0 * v0 + v1 * v1 + v2 * v2;
  __syncthreads();
  for (int off = 128; off; off >>= 1) {
    if (tid < off) {
      rs[tid] += rs[tid + off];
      rq[tid] += rq[tid + off];
    }
    __syncthreads();
  }
  float mu = rs[0] * (1.f / C_);
  float var = rq[0] * (1.f / C_) - mu * mu;
  float rstd = rsqrtf(var + 1e-5f);
  bf16* q = out + (size_t)row * C_;
  q[tid] = (bf16)((v0 - mu) * rstd * g[tid] + be[tid]);
  q[tid + 256] = (bf16)((v1 - mu) * rstd * g[tid + 256] + be[tid + 256]);
  q[tid + 512] = (bf16)((v2 - mu) * rstd * g[tid + 512] + be[tid + 512]);
}

// batched 2D transpose via LDS: out[b][cc][r] = in[b][r][cc]
__global__ __launch_bounds__(256) void transpose_f32(
    const float* __restrict__ in, float* __restrict__ out, int R, int Cc) {
  __shared__ float tile[32][33];
  int b = blockIdx.z;
  const float* ip = in + (size_t)b * R * Cc;
  float* op = out + (size_t)b * R * Cc;
  int c0 = blockIdx.x * 32, r0 = blockIdx.y * 32;
  int tx = threadIdx.x & 31, ty = threadIdx.x >> 5;
#pragma unroll
  for (int i = 0; i < 32; i += 8)
    tile[ty + i][tx] = ip[(size_t)(r0 + ty + i) * Cc + c0 + tx];
  __syncthreads();
#pragma unroll
  for (int i = 0; i < 32; i += 8)
    op[(size_t)(c0 + ty + i) * R + r0 + tx] = tile[tx][ty + i];
}

// ---------------------------------------------------------------------------
extern "C" void kernel_launch(void* const* d_in, const int* in_sizes, int n_in,
                              void* d_out, int out_size, void* d_ws,
                              size_t ws_size, hipStream_t stream) {
  (void)in_sizes; (void)n_in; (void)out_size; (void)ws_size;
  const float* x      = (const float*)d_in[0];
  const float* conv_w = (const float*)d_in[1];
  const float* conv_b = (const float*)d_in[2];
  const float* ln1_g  = (const float*)d_in[3];
  const float* ln1_b  = (const float*)d_in[4];
  const float* qkv_w  = (const float*)d_in[5];
  const float* proj_w = (const float*)d_in[6];
  const float* proj_b = (const float*)d_in[7];
  const float* ln2_g  = (const float*)d_in[8];
  const float* ln2_b  = (const float*)d_in[9];
  const float* fc1_w  = (const float*)d_in[10];
  const float* fc1_b  = (const float*)d_in[11];
  const float* fc2_w  = (const float*)d_in[12];
  const float* fc2_b  = (const float*)d_in[13];
  float* out = (float*)d_out;

  char* w = (char*)d_ws;
  auto carve = [&](size_t bytes) {
    char* p = w;
    w += (bytes + 255) & ~(size_t)255;
    return p;
  };
  bf16* hid   = (bf16*)carve((size_t)NTOK * HID_ * 2);   // 50.3 MB
  float* t0   = (float*)carve((size_t)NTOK * C_ * 4);    // residual fp32
  bf16* lnout = (bf16*)carve((size_t)NTOK * C_ * 2);
  bf16* wq    = (bf16*)carve((size_t)3 * C_ * C_ * 2);   // wq/wp/w1/w2 contiguous
  bf16* wp    = (bf16*)carve((size_t)C_ * C_ * 2);
  bf16* w1    = (bf16*)carve((size_t)HID_ * C_ * 2);
  bf16* w2    = (bf16*)carve((size_t)C_ * HID_ * 2);
  bf16* Qb    = (bf16*)carve((size_t)NHEADS * N_ * HD_ * 2);
  bf16* Kb    = (bf16*)carve((size_t)NHEADS * N_ * HD_ * 2);
  bf16* Vt    = (bf16*)carve((size_t)NHEADS * HD_ * N_ * 2);
  bf16* attn  = (bf16*)carve((size_t)NTOK * C_ * 2);

  const int na = 3 * C_ * C_, nb = C_ * C_, nc = HID_ * C_, nd = C_ * HID_;
  cast_all<<<(na + nb + nc + nd) / 1024, 256, 0, stream>>>(
      qkv_w, na, proj_w, nb, fc1_w, nc, fc2_w, wq);

  conv_pe_t<<<dim3(32, C_ / 32, B_), 256, 0, stream>>>(x, conv_w, conv_b, t0);

  ln_bf16<<<NTOK, 256, 0, stream>>>(t0, ln1_g, ln1_b, lnout);
  gemm_bt<2, 2, 0><<<dim3(3 * C_ / 128, NTOK / 128), 256, 0, stream>>>(
      lnout, wq, 768, 768, 768, Qb, Kb, Vt, nullptr, nullptr);

  flash_attn<<<dim3(N_ / 128, NHEADS), 256, 0, stream>>>(Qb, Kb, Vt, attn);

  // proj / fc2: 64x128 tiles -> 768 blocks (3/CU, fully resident)
  gemm_bt<1, 2, 3><<<dim3(C_ / 128, NTOK / 64), 128, 0, stream>>>(
      attn, wp, 768, 768, 768, nullptr, nullptr, nullptr, t0, proj_b);
  ln_bf16<<<NTOK, 256, 0, stream>>>(t0, ln2_g, ln2_b, lnout);
  gemm_bt<2, 2, 4><<<dim3(HID_ / 128, NTOK / 128), 256, 0, stream>>>(
      lnout, w1, 768, 768, 768, hid, nullptr, nullptr, nullptr, fc1_b);
  gemm_bt<1, 2, 3><<<dim3(C_ / 128, NTOK / 64), 128, 0, stream>>>(
      hid, w2, 3072, 3072, 3072, nullptr, nullptr, nullptr, t0, fc2_b);

  transpose_f32<<<dim3(C_ / 32, N_ / 32, B_), 256, 0, stream>>>(t0, out, N_, C_);
}